// Round 3
// baseline (45.904 us; speedup 1.0000x reference)
//
#include <hip/hip_runtime.h>

// WeightedBoxPool, single fused kernel.
//   j loses threshold t  <=>  max_{i beats j} fl(iou(i,j)) >= t,
//   beat = score_i>score_j || (score_i==score_j && i<j)  (argmax tie-break)
//       <=> key_i > key_j with key = (score_bits<<32) | (0x7fffffff - idx)
// Running max kept division-free as (nb,db) with cross-multiply compare;
// one IEEE f32 divide per (j, i-chunk); atomicMax(uint) across chunks
// (q >= 0 so uint-order == float-order). Final q>=t compare is bit-identical
// to the reference's per-i quotient comparisons.
// Last block per (b,jc) column finalizes: reads maxq coherently and writes out.

constexpr int ILEN = 64;    // i-boxes per chunk (grid.z)
constexpr int JBLK = 256;   // threads per block, one j each

__global__ __launch_bounds__(JBLK)
void wbp_fused(const float* __restrict__ box,     // [B,4,N]
               const float* __restrict__ score,   // [B,1,N]
               const float* __restrict__ mw,      // [B,T,N]
               const float* __restrict__ thr,     // [T]
               unsigned int* __restrict__ maxq,   // [B*N]   (pre-zeroed)
               unsigned int* __restrict__ cnt,    // [B*JC]  (pre-zeroed)
               float* __restrict__ out,           // [B*N]
               int N, int T, int IC)
{
    const int jc  = blockIdx.x;
    const int b   = blockIdx.y;
    const int tid = threadIdx.x;
    const int j   = jc * JBLK + tid;
    const int i0  = blockIdx.z * ILEN;
    const int icnt = min(ILEN, N - i0);
    const bool active = j < N;

    const float* __restrict__ bx1 = box + (size_t)(b * 4 + 0) * N;
    const float* __restrict__ by1 = box + (size_t)(b * 4 + 1) * N;
    const float* __restrict__ bx2 = box + (size_t)(b * 4 + 2) * N;
    const float* __restrict__ by2 = box + (size_t)(b * 4 + 3) * N;
    const float* __restrict__ sc  = score + (size_t)b * N;

    float jx1 = 0.f, jy1 = 0.f, jx2 = 0.f, jy2 = 0.f, ja = 0.f;
    unsigned long long jkey = ~0ull;   // inactive lanes: nothing can beat -> nb stays 0
    if (active) {
        jx1 = bx1[j]; jy1 = by1[j]; jx2 = bx2[j]; jy2 = by2[j];
        ja  = (jx2 - jx1) * (jy2 - jy1);
        jkey = ((unsigned long long)__float_as_uint(sc[j]) << 32)
             | (unsigned int)(0x7fffffff - j);
    }

    float nb = 0.f, db = 1.f;   // running max quotient nb/db over beating i

    auto body = [&](int k) {
        const int i = i0 + k;
        const float ix1 = bx1[i], iy1 = by1[i];       // block-uniform -> scalar loads
        const float ix2 = bx2[i], iy2 = by2[i];
        const float is  = sc[i];
        const unsigned long long ikey =
            ((unsigned long long)__float_as_uint(is) << 32)
            | (unsigned int)(0x7fffffff - i);
        const float ia  = (ix2 - ix1) * (iy2 - iy1);  // same expr as reference area
        const float ltx = fmaxf(jx1, ix1);
        const float lty = fmaxf(jy1, iy1);
        const float rbx = fminf(jx2, ix2);
        const float rby = fminf(jy2, iy2);
        const float w   = fmaxf(rbx - ltx, 0.f);
        const float h   = fmaxf(rby - lty, 0.f);
        const float inter = w * h;
        const float uni   = (ja + ia) - inter;        // fl symmetric == ref order
        const bool take = (ikey > jkey) && (inter * db > nb * uni);
        if (take) { nb = inter; db = uni; }           // branchless cndmask pair
    };

    if (icnt == ILEN) {
        #pragma unroll 8
        for (int k = 0; k < ILEN; ++k) body(k);
    } else {
        for (int k = 0; k < icnt; ++k) body(k);
    }

    if (active && nb > 0.f) {
        const float q = nb / db;                      // IEEE f32 divide, once per chunk
        atomicMax(&maxq[(size_t)b * N + j], __float_as_uint(q));
    }

    // ---- last-block-per-column finalize ----
    __shared__ int is_last;
    __syncthreads();          // drains vmcnt: all this block's atomics complete
    if (tid == 0) {
        __threadfence();
        const unsigned int old = atomicAdd(&cnt[b * gridDim.x + jc], 1u);
        is_last = (old == (unsigned int)(IC - 1));
    }
    __syncthreads();
    if (is_last && active) {
        __threadfence();
        const unsigned int qb = atomicMax(&maxq[(size_t)b * N + j], 0u); // coherent read
        const float q = __uint_as_float(qb);
        float acc = 0.f;
        for (int t = 0; t < T; ++t)
            if (q < thr[t])                           // survived threshold t
                acc += mw[(size_t)(b * T + t) * N + j];
        out[(size_t)b * N + j] = acc;
    }
}

extern "C" void kernel_launch(void* const* d_in, const int* in_sizes, int n_in,
                              void* d_out, int out_size, void* d_ws, size_t ws_size,
                              hipStream_t stream)
{
    const float* mw  = (const float*)d_in[0];   // [B,T,N]
    const float* box = (const float*)d_in[1];   // [B,4,N]
    const float* sc  = (const float*)d_in[2];   // [B,1,N]
    const float* thr = (const float*)d_in[3];   // [T]
    float* out = (float*)d_out;                 // [B,1,N]

    const int BN = in_sizes[2];
    const int T  = in_sizes[3];
    const int B  = 4;
    const int N  = BN / B;

    const int JC = (N + JBLK - 1) / JBLK;
    const int IC = (N + ILEN - 1) / ILEN;

    unsigned int* maxq = (unsigned int*)d_ws;                 // BN u32
    unsigned int* cnt  = maxq + BN;                           // B*JC u32

    hipMemsetAsync(d_ws, 0, (size_t)(BN + B * JC) * sizeof(unsigned int), stream);

    dim3 grid(JC, B, IC);
    wbp_fused<<<grid, JBLK, 0, stream>>>(box, sc, mw, thr, maxq, cnt, out, N, T, IC);
}

// Round 4
// 26.927 us; speedup vs baseline: 1.7047x; 1.7047x over previous
//
#include <hip/hip_runtime.h>

// WeightedBoxPool, single kernel, no atomics, no workspace.
//   out[b,j] = sum_t mask_weight[b,t,j] * [ max_{i beats j} fl(iou(i,j)) < thr[t] ]
//   beat = score_i>score_j || (score_i==score_j && i<j)
//        <=> key_i > key_j, key = (score_bits<<32) | (0x7fffffff - idx)  (scores > 0)
// Block = 16 j-columns x 16 i-subchunks (256 thr). Each thread scans its
// subchunk keeping a division-free running max (nb,db) via cross-multiply;
// one IEEE f32 divide per thread at the end; 16-way fmax reduce in LDS
// (rounding is monotone, so max of correctly-rounded chunk quotients >= t
//  iff some per-i quotient >= t — bit-identical to the reference compares).

constexpr int JROWS = 16;                 // j columns per block
constexpr int KSUB  = 16;                 // i subchunks per block
constexpr int TILE  = 16;                 // records staged per subchunk per step
constexpr int NTHR  = JROWS * KSUB;       // 256
constexpr int RSTR  = TILE * 8 + 8;       // LDS row stride (floats): +8 => 8-bank
                                          // shift per subchunk => conflict-free b128

__global__ __launch_bounds__(NTHR)
void wbp_kernel(const float* __restrict__ box,    // [B,4,N]
                const float* __restrict__ score,  // [B,1,N]
                const float* __restrict__ mw,     // [B,T,N]
                const float* __restrict__ thr,    // [T]
                float* __restrict__ out,          // [B,1,N]
                int N, int T)
{
    const int b     = blockIdx.y;
    const int jlane = threadIdx.x & (JROWS - 1);
    const int isub  = threadIdx.x >> 4;
    const int j     = blockIdx.x * JROWS + jlane;

    const int CH   = (N + KSUB - 1) / KSUB;       // i's per subchunk
    const int ibeg = isub * CH;
    const int iend = min(N, ibeg + CH);
    const int D    = (CH + TILE - 1) / TILE;

    __shared__ float tile[KSUB][RSTR];            // rec: x1 y1 x2 y2 area klo khi 0
    __shared__ float pq[JROWS][KSUB + 1];

    const float* __restrict__ bx1 = box + (size_t)(b * 4 + 0) * N;
    const float* __restrict__ by1 = box + (size_t)(b * 4 + 1) * N;
    const float* __restrict__ bx2 = box + (size_t)(b * 4 + 2) * N;
    const float* __restrict__ by2 = box + (size_t)(b * 4 + 3) * N;
    const float* __restrict__ sc  = score + (size_t)b * N;

    float jx1 = 0.f, jy1 = 0.f, jx2 = 0.f, jy2 = 0.f, ja = 0.f;
    unsigned long long jkey = ~0ull;              // j >= N: unbeatable -> q stays 0
    if (j < N) {
        jx1 = bx1[j]; jy1 = by1[j]; jx2 = bx2[j]; jy2 = by2[j];
        ja  = (jx2 - jx1) * (jy2 - jy1);
        jkey = ((unsigned long long)__float_as_uint(sc[j]) << 32)
             | (unsigned int)(0x7fffffff - j);
    }

    // staging prefetch registers (this thread stages slot jlane of row isub)
    float px1 = 0.f, py1 = 0.f, px2 = 0.f, py2 = 0.f, ps = 0.f;
    bool  pval = false;

    auto issue = [&](int d) {
        const int ii = ibeg + d * TILE + jlane;
        pval = ii < iend;
        const int ic = min(ii, N - 1);
        px1 = bx1[ic]; py1 = by1[ic]; px2 = bx2[ic]; py2 = by2[ic]; ps = sc[ic];
    };
    auto write_tile = [&](int d) {
        float* rec = &tile[isub][jlane * 8];
        if (pval) {
            const int ii = ibeg + d * TILE + jlane;
            rec[0] = px1; rec[1] = py1; rec[2] = px2; rec[3] = py2;
            rec[4] = (px2 - px1) * (py2 - py1);   // same expr as reference area
            ((unsigned int*)rec)[5] = 0x7fffffffu - (unsigned int)ii;
            ((unsigned int*)rec)[6] = __float_as_uint(ps);
            rec[7] = 0.f;
        } else {
            #pragma unroll
            for (int q = 0; q < 8; ++q) rec[q] = 0.f;  // inter=0, key=0: never wins
        }
    };

    float nb = 0.f, db = 1.f;                     // running max quotient nb/db

    issue(0);
    for (int d = 0; d < D; ++d) {
        write_tile(d);
        __syncthreads();
        if (d + 1 < D) issue(d + 1);

        #pragma unroll
        for (int k = 0; k < TILE; ++k) {
            const float4 r0 = *(const float4*)&tile[isub][k * 8];      // xyxy
            const float4 r1 = *(const float4*)&tile[isub][k * 8 + 4];  // area,klo,khi
            const unsigned long long ikey =
                ((unsigned long long)__float_as_uint(r1.z) << 32)
                | __float_as_uint(r1.y);
            const float ltx = fmaxf(jx1, r0.x);
            const float lty = fmaxf(jy1, r0.y);
            const float rbx = fminf(jx2, r0.z);
            const float rby = fminf(jy2, r0.w);
            const float w   = fmaxf(rbx - ltx, 0.f);
            const float h   = fmaxf(rby - lty, 0.f);
            const float inter = w * h;
            const float uni   = (ja + r1.x) - inter;
            const bool take = (ikey > jkey) && (inter * db > nb * uni);
            if (take) { nb = inter; db = uni; }   // branchless cndmask pair
        }
        __syncthreads();
    }

    // one IEEE divide per thread; reduce 16 partial quotients per column
    pq[jlane][isub] = (nb > 0.f) ? (nb / db) : 0.f;
    __syncthreads();

    if (threadIdx.x < JROWS && j < N) {
        float qm = 0.f;
        #pragma unroll
        for (int s = 0; s < KSUB; ++s) qm = fmaxf(qm, pq[threadIdx.x][s]);
        float acc = 0.f;
        for (int t = 0; t < T; ++t)
            if (qm < thr[t])                       // survived threshold t
                acc += mw[(size_t)(b * T + t) * N + j];
        out[(size_t)b * N + j] = acc;
    }
}

extern "C" void kernel_launch(void* const* d_in, const int* in_sizes, int n_in,
                              void* d_out, int out_size, void* d_ws, size_t ws_size,
                              hipStream_t stream)
{
    const float* mw  = (const float*)d_in[0];   // [B,T,N]
    const float* box = (const float*)d_in[1];   // [B,4,N]
    const float* sc  = (const float*)d_in[2];   // [B,1,N]
    const float* thr = (const float*)d_in[3];   // [T]
    float* out = (float*)d_out;                 // [B,1,N]

    const int BN = in_sizes[2];
    const int T  = in_sizes[3];
    const int B  = 4;                           // problem constant
    const int N  = BN / B;

    dim3 grid((N + JROWS - 1) / JROWS, B);
    wbp_kernel<<<grid, NTHR, 0, stream>>>(box, sc, mw, thr, out, N, T);
}

// Round 5
// 21.544 us; speedup vs baseline: 2.1307x; 1.2499x over previous
//
#include <hip/hip_runtime.h>

// WeightedBoxPool, single kernel, no LDS staging, no atomics, no workspace.
//   out[b,j] = sum_t mask_weight[b,t,j] * [ max_{i beats j} fl(iou(i,j)) < thr[t] ]
//   beat = score_i>score_j || (score_i==score_j && i<j)
//        <=> key_i > key_j, key = (score_bits<<32) | (0x7fffffff - idx)  (scores > 0)
// Block = 256 threads owning JG=4 consecutive j's; each thread scans i = i0+tid
// (stride 256, coalesced, L1/L2-resident) and keeps JG division-free running
// maxes (nb,db) via cross-multiply compare. One IEEE f32 divide per (lane,j),
// then shfl_xor wave max-reduce + tiny LDS cross-wave reduce. Rounding is
// monotone, so max of correctly-rounded chunk quotients >= t iff some per-i
// quotient >= t — bit-identical to the reference's compares (absmax 0.0 in r2-r4).

constexpr int JG   = 4;            // j columns per block
constexpr int NW   = 4;            // waves per block
constexpr int NTHR = NW * 64;      // 256

__global__ __launch_bounds__(NTHR)
void wbp_kernel(const float* __restrict__ box,    // [B,4,N]
                const float* __restrict__ score,  // [B,1,N]
                const float* __restrict__ mw,     // [B,T,N]
                const float* __restrict__ thr,    // [T]
                float* __restrict__ out,          // [B,1,N]
                int N, int T)
{
    const int b     = blockIdx.y;
    const int jbase = blockIdx.x * JG;
    const int tid   = threadIdx.x;
    const int lane  = tid & 63;
    const int wave  = tid >> 6;

    const float* __restrict__ bx1 = box + (size_t)(b * 4 + 0) * N;
    const float* __restrict__ by1 = box + (size_t)(b * 4 + 1) * N;
    const float* __restrict__ bx2 = box + (size_t)(b * 4 + 2) * N;
    const float* __restrict__ by2 = box + (size_t)(b * 4 + 3) * N;
    const float* __restrict__ sc  = score + (size_t)b * N;

    // j-state in registers (block-uniform addresses -> scalar loads)
    float jx1[JG], jy1[JG], jx2[JG], jy2[JG], ja[JG];
    unsigned long long jkey[JG];
    #pragma unroll
    for (int u = 0; u < JG; ++u) {
        const int j  = jbase + u;
        const int jc = min(j, N - 1);
        jx1[u] = bx1[jc]; jy1[u] = by1[jc]; jx2[u] = bx2[jc]; jy2[u] = by2[jc];
        ja[u]  = (jx2[u] - jx1[u]) * (jy2[u] - jy1[u]);
        jkey[u] = (j < N)
            ? (((unsigned long long)__float_as_uint(sc[jc]) << 32)
               | (unsigned int)(0x7fffffff - j))
            : ~0ull;                              // j OOB: unbeatable -> q stays 0
    }

    float nb[JG], db[JG];                         // running max quotient nb/db per j
    #pragma unroll
    for (int u = 0; u < JG; ++u) { nb[u] = 0.f; db[u] = 1.f; }

    // hot loop: no barriers, no LDS; i-record loaded once, reused for JG j's
    for (int i0 = 0; i0 < N; i0 += NTHR) {
        const int i  = i0 + tid;
        const int ic = min(i, N - 1);
        const float ix1 = bx1[ic], iy1 = by1[ic];
        const float ix2 = bx2[ic], iy2 = by2[ic];
        const float is  = sc[ic];
        const unsigned long long ikey = (i < N)
            ? (((unsigned long long)__float_as_uint(is) << 32)
               | (unsigned int)(0x7fffffff - i))
            : 0ull;                               // OOB: key 0 never beats
        const float ia = (ix2 - ix1) * (iy2 - iy1);   // same expr as reference area

        #pragma unroll
        for (int u = 0; u < JG; ++u) {
            const float ltx = fmaxf(jx1[u], ix1);
            const float lty = fmaxf(jy1[u], iy1);
            const float rbx = fminf(jx2[u], ix2);
            const float rby = fminf(jy2[u], iy2);
            const float w   = fmaxf(rbx - ltx, 0.f);
            const float h   = fmaxf(rby - lty, 0.f);
            const float inter = w * h;
            const float uni   = (ja[u] + ia) - inter;
            const bool take = (ikey > jkey[u]) && (inter * db[u] > nb[u] * uni);
            if (take) { nb[u] = inter; db[u] = uni; }   // branchless cndmask pair
        }
    }

    // one IEEE divide per (lane, j); wave-level max reduce via shuffles
    __shared__ float pq[NW][JG];
    float qr[JG];
    #pragma unroll
    for (int u = 0; u < JG; ++u) {
        float q = (nb[u] > 0.f) ? (nb[u] / db[u]) : 0.f;
        #pragma unroll
        for (int m = 32; m >= 1; m >>= 1)
            q = fmaxf(q, __shfl_xor(q, m, 64));
        qr[u] = q;
    }
    if (lane == 0) {
        #pragma unroll
        for (int u = 0; u < JG; ++u) pq[wave][u] = qr[u];
    }
    __syncthreads();

    if (tid < JG) {
        const int j = jbase + tid;
        if (j < N) {
            const float qm = fmaxf(fmaxf(pq[0][tid], pq[1][tid]),
                                   fmaxf(pq[2][tid], pq[3][tid]));
            float acc = 0.f;
            for (int t = 0; t < T; ++t)
                if (qm < thr[t])                  // survived threshold t
                    acc += mw[(size_t)(b * T + t) * N + j];
            out[(size_t)b * N + j] = acc;
        }
    }
}

extern "C" void kernel_launch(void* const* d_in, const int* in_sizes, int n_in,
                              void* d_out, int out_size, void* d_ws, size_t ws_size,
                              hipStream_t stream)
{
    const float* mw  = (const float*)d_in[0];   // [B,T,N]
    const float* box = (const float*)d_in[1];   // [B,4,N]
    const float* sc  = (const float*)d_in[2];   // [B,1,N]
    const float* thr = (const float*)d_in[3];   // [T]
    float* out = (float*)d_out;                 // [B,1,N]

    const int BN = in_sizes[2];
    const int T  = in_sizes[3];
    const int B  = 4;                           // problem constant
    const int N  = BN / B;

    dim3 grid((N + JG - 1) / JG, B);
    wbp_kernel<<<grid, NTHR, 0, stream>>>(box, sc, mw, thr, out, N, T);
}